// Round 10
// baseline (177.032 us; speedup 1.0000x reference)
//
#include <hip/hip_runtime.h>
#include <hip/hip_fp16.h>

#define N_NODES 50000
#define N_EDGES 800000
#define N_GRAPHS 256
#define NCB 196        // coarse buckets = ceil(50000/256), dst>>8
#define CHUNK 3125     // edges per block in coarse passes (256 blocks)
#define MBLK 782       // ceil(50000/64)

typedef _Float16 f16x8 __attribute__((ext_vector_type(8)));
typedef float    f32x4 __attribute__((ext_vector_type(4)));

// ---------------------------------------------------------------------------
// hist_prep: blocks 0..255 coarse edge histogram (dst>>8); then vectorized
// XPh pad, bounds, fp16 fragment-packed weights, PS zero.
// ---------------------------------------------------------------------------
__global__ __launch_bounds__(256)
void hist_prep(const int* __restrict__ ER, const float* __restrict__ X,
               const int* __restrict__ SEG,
               const float* __restrict__ W1, const float* __restrict__ W2,
               const float* __restrict__ W12, const float* __restrict__ W22,
               const float* __restrict__ W13, const float* __restrict__ W23,
               int* __restrict__ ghist, __half* __restrict__ XPh,
               int* __restrict__ start,
               __half* __restrict__ W1f, __half* __restrict__ W2f,
               __half* __restrict__ W3f, float* __restrict__ PS)
{
    int b = blockIdx.x;
    int t = threadIdx.x;
    if (b < 256) {                           // coarse histogram
        __shared__ int h[NCB];
        for (int i = t; i < NCB; i += 256) h[i] = 0;
        __syncthreads();
        int lo = b * CHUNK, hi = lo + CHUNK;
        for (int e = lo + t; e < hi; e += 256) atomicAdd(&h[ER[e] >> 8], 1);
        __syncthreads();
        for (int i = t; i < NCB; i += 256) ghist[i * 256 + b] = h[i];
        return;
    }
    int bid = b - 256;
    if (bid < 782) {                         // pad: XPh fp16, 8 halves/thread
        int idx = bid * 256 + t;             // one uint4 of XPh
        int n = idx >> 2;
        int c4 = idx & 3;
        if (n >= N_NODES) return;
        __half2 hb[4];
        #pragma unroll
        for (int k = 0; k < 4; ++k) {
            int c0 = c4 * 8 + 2 * k;
            float v0 = (c0 < 30) ? X[n * 30 + c0] : 0.f;
            float v1 = (c0 + 1 < 30) ? X[n * 30 + c0 + 1] : 0.f;
            hb[k] = __float22half2_rn(make_float2(v0, v1));
        }
        *(uint4*)(XPh + (size_t)n * 32 + c4 * 8) = *(uint4*)&hb[0];
    } else if (bid < 978) {                  // bounds from sorted seg
        int n = (bid - 782) * 256 + t;
        if (n >= N_NODES) return;
        int g = SEG[n];
        int gprev = (n == 0) ? -1 : SEG[n - 1];
        for (int gg = gprev + 1; gg <= g; ++gg) start[gg] = n;
        if (n == N_NODES - 1)
            for (int gg = g + 1; gg <= N_GRAPHS; ++gg) start[gg] = N_NODES;
    } else if (bid < 1090) {                 // fragment-packed fp16 weights
        int idx = (bid - 978) * 256 + t;     // 0 .. 28671
        if (idx < 8192) {                    // W1f: 64x128 ([W1_1;pad;W2_1])
            int i = idx & 7, c = (idx >> 3) & 15, g = (idx >> 7) & 3;
            int s = (idx >> 9) & 1, n = idx >> 10;
            int k = s * 32 + g * 8 + i, col = n * 16 + c;
            float w = 0.f;
            if (k < 30) w = W1[k * 128 + col];
            else if (k >= 32 && k < 62) w = W2[(k - 32) * 128 + col];
            W1f[idx] = __float2half(w);
        } else if (idx < 24576) {            // W2f: 128x128 ([W1_2|W2_2])
            int o = idx - 8192;
            int i = o & 7, c = (o >> 3) & 15, g = (o >> 7) & 3;
            int s = (o >> 9) & 3, n = o >> 11;
            int k = s * 32 + g * 8 + i, col = n * 16 + c;
            float w = (col < 64) ? W12[k * 64 + col] : W22[k * 64 + col - 64];
            W2f[o] = __float2half(w);
        } else {                             // W3f: 64x64 ([W1_3|W2_3])
            int o = idx - 24576;
            int i = o & 7, c = (o >> 3) & 15, g = (o >> 7) & 3;
            int s = (o >> 9) & 1, n = o >> 10;
            int k = s * 32 + g * 8 + i, col = n * 16 + c;
            float w = (col < 32) ? W13[k * 32 + col] : W23[k * 32 + col - 32];
            W3f[o] = __float2half(w);
        }
    } else {                                 // zero pooled-sum buffer
        int idx = (bid - 1090) * 256 + t;    // 0 .. 8191
        PS[idx] = 0.f;
    }
}

// ---------------------------------------------------------------------------
// scan1: per-bucket exclusive scan of the 256 per-block counts, in place;
// bucket total -> bsum[b].
// ---------------------------------------------------------------------------
__global__ __launch_bounds__(256)
void scan1(int* __restrict__ ghist, int* __restrict__ bsum)
{
    __shared__ int s[256];
    int t = threadIdx.x, b = blockIdx.x;
    int i = b * 256 + t;
    int v = ghist[i];
    s[t] = v;
    __syncthreads();
    for (int off = 1; off < 256; off <<= 1) {
        int u = (t >= off) ? s[t - off] : 0;
        __syncthreads();
        s[t] += u;
        __syncthreads();
    }
    ghist[i] = s[t] - v;
    if (t == 255) bsum[b] = s[255];
}

// ---------------------------------------------------------------------------
// c_scatter: coarse scatter into per-block contiguous runs.
// tmp = { src | ((dst&255)<<16), fp16 weight } as one 8B uint2 store.
// ---------------------------------------------------------------------------
__global__ __launch_bounds__(256)
void c_scatter(const int* __restrict__ ER, const int* __restrict__ EC,
               const float* __restrict__ EW, const int* __restrict__ ghist,
               const int* __restrict__ bsum, uint2* __restrict__ tmp)
{
    __shared__ int s[256];
    __shared__ int cur[NCB];
    int t = threadIdx.x, blk = blockIdx.x;
    int v = (t < NCB) ? bsum[t] : 0;
    s[t] = v;
    __syncthreads();
    for (int off = 1; off < 256; off <<= 1) {
        int u = (t >= off) ? s[t - off] : 0;
        __syncthreads();
        s[t] += u;
        __syncthreads();
    }
    if (t < NCB) cur[t] = (s[t] - v) + ghist[t * 256 + blk];
    __syncthreads();
    int lo = blk * CHUNK, hi = lo + CHUNK;
    for (int e = lo + t; e < hi; e += 256) {
        int d = ER[e];
        int pos = atomicAdd(&cur[d >> 8], 1);
        tmp[pos] = make_uint2((unsigned int)EC[e] | ((unsigned int)(d & 255) << 16),
                              (unsigned int)__half_as_ushort(__float2half(EW[e])));
    }
}

// ---------------------------------------------------------------------------
// fp16 gather helper
// ---------------------------------------------------------------------------
__device__ __forceinline__ void fma8h(float4& a0, float4& a1, float w,
                                      const uint4& raw)
{
    const __half2* hp = (const __half2*)&raw;
    float2 f0 = __half22float2(hp[0]);
    float2 f1 = __half22float2(hp[1]);
    float2 f2 = __half22float2(hp[2]);
    float2 f3 = __half22float2(hp[3]);
    a0.x = fmaf(w, f0.x, a0.x); a0.y = fmaf(w, f0.y, a0.y);
    a0.z = fmaf(w, f1.x, a0.z); a0.w = fmaf(w, f1.y, a0.w);
    a1.x = fmaf(w, f2.x, a1.x); a1.y = fmaf(w, f2.y, a1.y);
    a1.z = fmaf(w, f3.x, a1.z); a1.w = fmaf(w, f3.y, a1.w);
}

// ---------------------------------------------------------------------------
// bsort (1024 thr): per-bucket counting sort -> packed + rowptr.
// ---------------------------------------------------------------------------
__global__ __launch_bounds__(1024)
void bsort(const uint2* __restrict__ tmp, const int* __restrict__ bsum,
           unsigned int* __restrict__ packed, int* __restrict__ rowptr)
{
    __shared__ int s[256];
    __shared__ int hist[256];
    __shared__ int cur[256];
    int t = threadIdx.x, b = blockIdx.x;

    if (t < 256) s[t] = (t < NCB) ? bsum[t] : 0;
    __syncthreads();
    for (int off = 1; off < 256; off <<= 1) {
        int u = 0;
        if (t < 256 && t >= off) u = s[t - off];
        __syncthreads();
        if (t < 256) s[t] += u;
        __syncthreads();
    }
    int cntb = bsum[b];
    int base = s[b] - cntb;
    int end  = base + cntb;
    __syncthreads();

    if (t < 256) hist[t] = 0;
    __syncthreads();
    for (int j = base + t; j < end; j += 1024)
        atomicAdd(&hist[(tmp[j].x >> 16) & 255], 1);
    __syncthreads();
    int hv = 0;
    if (t < 256) { hv = hist[t]; s[t] = hv; }
    __syncthreads();
    for (int off = 1; off < 256; off <<= 1) {
        int u = 0;
        if (t < 256 && t >= off) u = s[t - off];
        __syncthreads();
        if (t < 256) s[t] += u;
        __syncthreads();
    }
    if (t < 256) {
        int excl = s[t] - hv;
        int n = b * 256 + t;
        if (n < N_NODES) rowptr[n] = base + excl;
        if (b == NCB - 1 && t == 0) rowptr[N_NODES] = N_EDGES;
        cur[t] = base + excl;
    }
    __syncthreads();
    for (int j = base + t; j < end; j += 1024) {
        uint2 v = tmp[j];
        int pos = atomicAdd(&cur[(v.x >> 16) & 255], 1);
        packed[pos] = (v.x & 0xFFFF) | (v.y << 16);
    }
}

// ---------------------------------------------------------------------------
// dense12_mfma (512 thr): layer-1 aggx (S=2 edge split) FUSED with layers 1+2
// dense on matrix cores, 8 waves. (unchanged from round 9)
// ---------------------------------------------------------------------------
__global__ __launch_bounds__(512)
void dense12_mfma(const __half* __restrict__ XPh, const int* __restrict__ rowptr,
                  const unsigned int* __restrict__ packed,
                  const __half* __restrict__ W1f, const float* __restrict__ B1,
                  const __half* __restrict__ W2f, const float* __restrict__ B2,
                  __half* __restrict__ H2h, __half* __restrict__ A2h)
{
    __shared__ __align__(16) __half As[64 * 72];    // input tile, stride 72
    __shared__ __align__(16) __half Hs[64 * 136];   // partials / h1 / output
    const int tid = threadIdx.x;
    const int m0 = blockIdx.x * 64;

    // phase 0a: stage XPh half (cols 32-63): 64 rows x 4 uint4 = 256 threads
    if (tid < 256) {
        int row = tid >> 2, c4 = tid & 3;
        int gm = m0 + row;
        uint4 v = make_uint4(0, 0, 0, 0);
        if (gm < N_NODES) v = *(const uint4*)(XPh + (size_t)gm * 32 + c4 * 8);
        *(uint4*)(As + row * 72 + (4 + c4) * 8) = v;
    }
    // phase 0b: layer-1 aggx, S=2 edge split: 64 nodes x 2 seg x 4 lanes.
    {
        int local = tid >> 3;          // node 0..63
        int es = (tid >> 2) & 1;       // edge segment
        int q = tid & 3;               // feature quad
        int n = m0 + local;
        float4 acc0 = make_float4(0.f, 0.f, 0.f, 0.f);
        float4 acc1 = make_float4(0.f, 0.f, 0.f, 0.f);
        if (n < N_NODES) {
            int r0 = rowptr[n], r1 = rowptr[n + 1];
            int mid = (r0 + r1) >> 1;
            int lo = es ? mid : r0;
            int hi = es ? r1 : mid;
            int j = lo;
            for (; j + 3 < hi; j += 4) {
                unsigned int ra = packed[j],     rb = packed[j + 1];
                unsigned int rc = packed[j + 2], rd = packed[j + 3];
                uint4 rawa = *(const uint4*)(XPh + (size_t)(ra & 0xFFFF) * 32 + q * 8);
                uint4 rawb = *(const uint4*)(XPh + (size_t)(rb & 0xFFFF) * 32 + q * 8);
                uint4 rawc = *(const uint4*)(XPh + (size_t)(rc & 0xFFFF) * 32 + q * 8);
                uint4 rawd = *(const uint4*)(XPh + (size_t)(rd & 0xFFFF) * 32 + q * 8);
                float wa = __half2float(__ushort_as_half((unsigned short)(ra >> 16)));
                float wb = __half2float(__ushort_as_half((unsigned short)(rb >> 16)));
                float wc = __half2float(__ushort_as_half((unsigned short)(rc >> 16)));
                float wd = __half2float(__ushort_as_half((unsigned short)(rd >> 16)));
                fma8h(acc0, acc1, wa, rawa);
                fma8h(acc0, acc1, wb, rawb);
                fma8h(acc0, acc1, wc, rawc);
                fma8h(acc0, acc1, wd, rawd);
            }
            for (; j < hi; ++j) {
                unsigned int r = packed[j];
                uint4 raw = *(const uint4*)(XPh + (size_t)(r & 0xFFFF) * 32 + q * 8);
                float wv = __half2float(__ushort_as_half((unsigned short)(r >> 16)));
                fma8h(acc0, acc1, wv, raw);
            }
        }
        float* part = (float*)Hs;      // 64 x 36 fp32 (9.2 KB < 17.4 KB)
        if (es == 1) {
            *(float4*)&part[local * 36 + q * 8 + 0] = acc0;
            *(float4*)&part[local * 36 + q * 8 + 4] = acc1;
        }
        __syncthreads();               // partials + 0a staging visible
        if (es == 0) {
            float4 p0 = *(float4*)&part[local * 36 + q * 8 + 0];
            float4 p1 = *(float4*)&part[local * 36 + q * 8 + 4];
            acc0.x += p0.x; acc0.y += p0.y; acc0.z += p0.z; acc0.w += p0.w;
            acc1.x += p1.x; acc1.y += p1.y; acc1.z += p1.z; acc1.w += p1.w;
            __half2 hb2[4];
            hb2[0] = __float22half2_rn(make_float2(acc0.x, acc0.y));
            hb2[1] = __float22half2_rn(make_float2(acc0.z, acc0.w));
            hb2[2] = __float22half2_rn(make_float2(acc1.x, acc1.y));
            hb2[3] = __float22half2_rn(make_float2(acc1.z, acc1.w));
            *(uint4*)(As + local * 72 + q * 8) = *(uint4*)&hb2[0];
        }
    }
    __syncthreads();                   // As complete; Hs free for h1

    const int lane = tid & 63;
    const int w  = tid >> 6;           // wave 0..7, owns n-subtile w
    const int lr = lane & 15;
    const int lg = lane >> 4;

    // phase A: K=64 (2 MFMA K-slices), 8 MFMAs/wave
    f32x4 acc[4];
    #pragma unroll
    for (int m = 0; m < 4; ++m) acc[m] = (f32x4){0.f, 0.f, 0.f, 0.f};

    #pragma unroll
    for (int s = 0; s < 2; ++s) {
        f16x8 b = *(const f16x8*)(W1f + (((w * 2 + s) * 4 + lg) * 16 + lr) * 8);
        #pragma unroll
        for (int m = 0; m < 4; ++m) {
            f16x8 a = *(const f16x8*)(As + (m * 16 + lr) * 72 + s * 32 + lg * 8);
            acc[m] = __builtin_amdgcn_mfma_f32_16x16x32_f16(a, b, acc[m], 0, 0, 0);
        }
    }

    // +b1, relu, h1 -> LDS fp16
    {
        const float bias = B1[w * 16 + lr];
        #pragma unroll
        for (int m = 0; m < 4; ++m)
            #pragma unroll
            for (int r = 0; r < 4; ++r) {
                float v = fmaxf(acc[m][r] + bias, 0.f);
                Hs[(m * 16 + lg * 4 + r) * 136 + w * 16 + lr] = __float2half(v);
            }
    }
    __syncthreads();

    // phase B: K=128 (4 slices), 16 MFMAs/wave
    f32x4 acc2[4];
    #pragma unroll
    for (int m = 0; m < 4; ++m) acc2[m] = (f32x4){0.f, 0.f, 0.f, 0.f};

    #pragma unroll
    for (int s = 0; s < 4; ++s) {
        f16x8 b = *(const f16x8*)(W2f + (((w * 4 + s) * 4 + lg) * 16 + lr) * 8);
        #pragma unroll
        for (int m = 0; m < 4; ++m) {
            f16x8 a = *(const f16x8*)(Hs + (m * 16 + lr) * 136 + s * 32 + lg * 8);
            acc2[m] = __builtin_amdgcn_mfma_f32_16x16x32_f16(a, b, acc2[m], 0, 0, 0);
        }
    }
    __syncthreads();   // all h1 reads done; Hs reusable for output

    {
        const float bias = (w >= 4) ? B2[(w - 4) * 16 + lr] : 0.f;
        #pragma unroll
        for (int m = 0; m < 4; ++m)
            #pragma unroll
            for (int r = 0; r < 4; ++r)
                Hs[(m * 16 + lg * 4 + r) * 136 + w * 16 + lr] =
                    __float2half(acc2[m][r] + bias);
    }
    __syncthreads();

    // coalesced fp16 store: cols 0-63 -> H2h, 64-127 -> A2h
    for (int idx = tid; idx < 1024; idx += 512) {
        int row = idx >> 4, c8 = idx & 15;
        int gm = m0 + row;
        if (gm < N_NODES) {
            uint4 v = *(const uint4*)(Hs + row * 136 + c8 * 8);
            if (c8 < 8) *(uint4*)(H2h + (size_t)gm * 64 + c8 * 8) = v;
            else        *(uint4*)(A2h + (size_t)gm * 64 + (c8 - 8) * 8) = v;
        }
    }
}

// ---------------------------------------------------------------------------
// spmm_dense3 (1024 thr): layer-2 SpMM (S=2 edge split, 16 thr/node) FUSED
// with layer-3 dense on matrix cores (16 waves). (unchanged from round 9)
// ---------------------------------------------------------------------------
__global__ __launch_bounds__(1024)
void spmm_dense3(const __half* __restrict__ H2h, const int* __restrict__ rowptr,
                 const unsigned int* __restrict__ packed,
                 const __half* __restrict__ A2h, const __half* __restrict__ W3f,
                 const float* __restrict__ B3, __half* __restrict__ H3h,
                 __half* __restrict__ B2h)
{
    __shared__ __align__(16) __half As[64 * 72];    // relu'd layer-2 act tile
    __shared__ __align__(16) __half Os[64 * 72];    // output tile
    __shared__ float part[64][68];                  // s=1 partials (17.4 KB)
    const int tid = threadIdx.x;
    const int m0 = blockIdx.x * 64;

    // ---- phase 1: SpMM, 64 nodes x 2 segments x 8 lanes ----
    {
        int local = tid >> 4;          // node 0..63
        int es = (tid >> 3) & 1;       // edge segment
        int q = tid & 7;               // feature octet (64 cols)
        int n = m0 + local;
        float4 acc0 = make_float4(0.f, 0.f, 0.f, 0.f);
        float4 acc1 = make_float4(0.f, 0.f, 0.f, 0.f);
        if (n < N_NODES) {
            int r0 = rowptr[n], r1 = rowptr[n + 1];
            int mid = (r0 + r1) >> 1;
            int lo = es ? mid : r0;
            int hi = es ? r1 : mid;
            if (es == 0) {             // init from A2h (x @ W2_2 + b2 part)
                uint4 raw = *(const uint4*)(A2h + (size_t)n * 64 + q * 8);
                const __half2* hp = (const __half2*)&raw;
                float2 f0 = __half22float2(hp[0]);
                float2 f1 = __half22float2(hp[1]);
                float2 f2 = __half22float2(hp[2]);
                float2 f3 = __half22float2(hp[3]);
                acc0 = make_float4(f0.x, f0.y, f1.x, f1.y);
                acc1 = make_float4(f2.x, f2.y, f3.x, f3.y);
            }
            int j = lo;
            for (; j + 3 < hi; j += 4) {
                unsigned int ra = packed[j],     rb = packed[j + 1];
                unsigned int rc = packed[j + 2], rd = packed[j + 3];
                uint4 rawa = *(const uint4*)(H2h + (size_t)(ra & 0xFFFF) * 64 + q * 8);
                uint4 rawb = *(const uint4*)(H2h + (size_t)(rb & 0xFFFF) * 64 + q * 8);
                uint4 rawc = *(const uint4*)(H2h + (size_t)(rc & 0xFFFF) * 64 + q * 8);
                uint4 rawd = *(const uint4*)(H2h + (size_t)(rd & 0xFFFF) * 64 + q * 8);
                float wa = __half2float(__ushort_as_half((unsigned short)(ra >> 16)));
                float wb = __half2float(__ushort_as_half((unsigned short)(rb >> 16)));
                float wc = __half2float(__ushort_as_half((unsigned short)(rc >> 16)));
                float wd = __half2float(__ushort_as_half((unsigned short)(rd >> 16)));
                fma8h(acc0, acc1, wa, rawa);
                fma8h(acc0, acc1, wb, rawb);
                fma8h(acc0, acc1, wc, rawc);
                fma8h(acc0, acc1, wd, rawd);
            }
            for (; j < hi; ++j) {
                unsigned int r = packed[j];
                uint4 raw = *(const uint4*)(H2h + (size_t)(r & 0xFFFF) * 64 + q * 8);
                float w = __half2float(__ushort_as_half((unsigned short)(r >> 16)));
                fma8h(acc0, acc1, w, raw);
            }
        }
        if (es == 1) {
            *(float4*)&part[local][q * 8 + 0] = acc0;
            *(float4*)&part[local][q * 8 + 4] = acc1;
        }
        __syncthreads();
        if (es == 0) {
            float4 p0 = *(float4*)&part[local][q * 8 + 0];
            float4 p1 = *(float4*)&part[local][q * 8 + 4];
            acc0.x += p0.x; acc0.y += p0.y; acc0.z += p0.z; acc0.w += p0.w;
            acc1.x += p1.x; acc1.y += p1.y; acc1.z += p1.z; acc1.w += p1.w;
            // relu + fp16 pack straight into the MFMA A-tile
            __half2 hb[4];
            hb[0] = __float22half2_rn(make_float2(fmaxf(acc0.x, 0.f), fmaxf(acc0.y, 0.f)));
            hb[1] = __float22half2_rn(make_float2(fmaxf(acc0.z, 0.f), fmaxf(acc0.w, 0.f)));
            hb[2] = __float22half2_rn(make_float2(fmaxf(acc1.x, 0.f), fmaxf(acc1.y, 0.f)));
            hb[3] = __float22half2_rn(make_float2(fmaxf(acc1.z, 0.f), fmaxf(acc1.w, 0.f)));
            *(uint4*)(As + local * 72 + q * 8) = *(uint4*)&hb[0];
        }
    }
    __syncthreads();

    // ---- phase 2: dense3 MFMA, 16 waves; wave w = (m-quarter w>>2, n w&3) ----
    const int lane = tid & 63;
    const int w  = tid >> 6;      // 0..15
    const int wm = w >> 2;        // m quarter
    const int wn = w & 3;         // n subtile
    const int lr = lane & 15;
    const int lg = lane >> 4;

    f32x4 acc = (f32x4){0.f, 0.f, 0.f, 0.f};
    #pragma unroll
    for (int s = 0; s < 2; ++s) {
        f16x8 b = *(const f16x8*)(W3f + (((wn * 2 + s) * 4 + lg) * 16 + lr) * 8);
        f16x8 a = *(const f16x8*)(As + (wm * 16 + lr) * 72 + s * 32 + lg * 8);
        acc = __builtin_amdgcn_mfma_f32_16x16x32_f16(a, b, acc, 0, 0, 0);
    }

    const float bias = (wn >= 2) ? B3[(wn - 2) * 16 + lr] : 0.f;
    #pragma unroll
    for (int r = 0; r < 4; ++r)
        Os[(wm * 16 + lg * 4 + r) * 72 + wn * 16 + lr] = __float2half(acc[r] + bias);
    __syncthreads();

    // store: 64 rows x 8 uint4 = 512 entries
    if (tid < 512) {
        int row = tid >> 3, c8 = tid & 7;
        int gm = m0 + row;
        if (gm < N_NODES) {
            uint4 v = *(const uint4*)(Os + row * 72 + c8 * 8);
            if (c8 < 4) *(uint4*)(H3h + (size_t)gm * 32 + c8 * 8) = v;
            else        *(uint4*)(B2h + (size_t)gm * 32 + (c8 - 4) * 8) = v;
        }
    }
}

// ---------------------------------------------------------------------------
// spmm_pool (1024 thr): layer-3 SpMM (S=4 edge split, 16 thr/node) FUSED with
// global-average pooling. B2h is read-only init (no write-back); relu'd rows
// accumulate into a 65-slot per-graph LDS buffer (nodes graph-sorted: a
// 64-node block spans <= 65 graphs), then one atomicAdd per (graph,feature).
// ---------------------------------------------------------------------------
__global__ __launch_bounds__(1024)
void spmm_pool(const __half* __restrict__ H, const int* __restrict__ rowptr,
               const unsigned int* __restrict__ packed,
               const __half* __restrict__ Bse, const int* __restrict__ SEG,
               float* __restrict__ PS)
{
    __shared__ float part[64][3][36];   // s>0 partials (27.6 KB)
    __shared__ float ps[65][32];        // per-graph sums (8.3 KB)
    const int tid = threadIdx.x;
    const int n0 = blockIdx.x * 64;

    for (int i = tid; i < 65 * 32; i += 1024) ((float*)ps)[i] = 0.f;

    int local = tid >> 4;          // node 0..63
    int s = (tid >> 2) & 3;        // edge segment 0..3
    int q = tid & 3;               // feature quad (32 cols)
    int n = n0 + local;
    bool valid = (n < N_NODES);
    float4 acc0 = make_float4(0.f, 0.f, 0.f, 0.f);
    float4 acc1 = make_float4(0.f, 0.f, 0.f, 0.f);
    if (valid) {
        int r0 = rowptr[n], r1 = rowptr[n + 1];
        int deg = r1 - r0;
        int lo = r0 + (deg * s) / 4;
        int hi = r0 + (deg * (s + 1)) / 4;
        if (s == 0) {                      // init from Bse (x @ W2_3 + b3)
            uint4 raw = *(const uint4*)(Bse + (size_t)n * 32 + q * 8);
            const __half2* hp = (const __half2*)&raw;
            float2 f0 = __half22float2(hp[0]);
            float2 f1 = __half22float2(hp[1]);
            float2 f2 = __half22float2(hp[2]);
            float2 f3 = __half22float2(hp[3]);
            acc0 = make_float4(f0.x, f0.y, f1.x, f1.y);
            acc1 = make_float4(f2.x, f2.y, f3.x, f3.y);
        }
        int j = lo;
        for (; j + 3 < hi; j += 4) {
            unsigned int ra = packed[j],     rb = packed[j + 1];
            unsigned int rc = packed[j + 2], rd = packed[j + 3];
            uint4 rawa = *(const uint4*)(H + (size_t)(ra & 0xFFFF) * 32 + q * 8);
            uint4 rawb = *(const uint4*)(H + (size_t)(rb & 0xFFFF) * 32 + q * 8);
            uint4 rawc = *(const uint4*)(H + (size_t)(rc & 0xFFFF) * 32 + q * 8);
            uint4 rawd = *(const uint4*)(H + (size_t)(rd & 0xFFFF) * 32 + q * 8);
            float wa = __half2float(__ushort_as_half((unsigned short)(ra >> 16)));
            float wb = __half2float(__ushort_as_half((unsigned short)(rb >> 16)));
            float wc = __half2float(__ushort_as_half((unsigned short)(rc >> 16)));
            float wd = __half2float(__ushort_as_half((unsigned short)(rd >> 16)));
            fma8h(acc0, acc1, wa, rawa);
            fma8h(acc0, acc1, wb, rawb);
            fma8h(acc0, acc1, wc, rawc);
            fma8h(acc0, acc1, wd, rawd);
        }
        for (; j < hi; ++j) {
            unsigned int r = packed[j];
            uint4 raw = *(const uint4*)(H + (size_t)(r & 0xFFFF) * 32 + q * 8);
            float w = __half2float(__ushort_as_half((unsigned short)(r >> 16)));
            fma8h(acc0, acc1, w, raw);
        }
    }
    if (s > 0) {
        *(float4*)&part[local][s - 1][q * 8 + 0] = acc0;
        *(float4*)&part[local][s - 1][q * 8 + 4] = acc1;
    }
    __syncthreads();                   // partials + ps zero visible
    int g0 = SEG[n0];
    if (s == 0 && valid) {
        #pragma unroll
        for (int ss = 0; ss < 3; ++ss) {
            float4 p0 = *(float4*)&part[local][ss][q * 8 + 0];
            float4 p1 = *(float4*)&part[local][ss][q * 8 + 4];
            acc0.x += p0.x; acc0.y += p0.y; acc0.z += p0.z; acc0.w += p0.w;
            acc1.x += p1.x; acc1.y += p1.y; acc1.z += p1.z; acc1.w += p1.w;
        }
        float* dst = &ps[SEG[n] - g0][q * 8];
        atomicAdd(&dst[0], fmaxf(acc0.x, 0.f));
        atomicAdd(&dst[1], fmaxf(acc0.y, 0.f));
        atomicAdd(&dst[2], fmaxf(acc0.z, 0.f));
        atomicAdd(&dst[3], fmaxf(acc0.w, 0.f));
        atomicAdd(&dst[4], fmaxf(acc1.x, 0.f));
        atomicAdd(&dst[5], fmaxf(acc1.y, 0.f));
        atomicAdd(&dst[6], fmaxf(acc1.z, 0.f));
        atomicAdd(&dst[7], fmaxf(acc1.w, 0.f));
    }
    __syncthreads();
    int nlast = n0 + 63;
    if (nlast >= N_NODES) nlast = N_NODES - 1;
    int span = SEG[nlast] - g0 + 1;
    for (int i = tid; i < span * 32; i += 1024) {
        float v = ps[i >> 5][i & 31];
        if (v != 0.f)
            atomicAdd(&PS[(size_t)(g0 + (i >> 5)) * 32 + (i & 31)], v);
    }
}

// ---------------------------------------------------------------------------
// head: one block; thread g: pooled = PS[g]/cnt, softmax(pooled @ wd + bd).
// ---------------------------------------------------------------------------
__global__ __launch_bounds__(256)
void head_kernel(const float* __restrict__ PS, const int* __restrict__ start,
                 const float* __restrict__ WD, const float* __restrict__ BD,
                 float* __restrict__ OUT)
{
    int g = threadIdx.x;
    int s = start[g], e = start[g + 1];
    float inv = (e > s) ? 1.0f / (float)(e - s) : 1.0f;
    float l0 = 0.f, l1 = 0.f;
    #pragma unroll
    for (int j = 0; j < 32; ++j) {
        float p = PS[g * 32 + j] * inv;
        l0 = fmaf(p, WD[j * 2 + 0], l0);
        l1 = fmaf(p, WD[j * 2 + 1], l1);
    }
    l0 += BD[0]; l1 += BD[1];
    float m = fmaxf(l0, l1);
    float e0 = expf(l0 - m), e1 = expf(l1 - m);
    float si = 1.0f / (e0 + e1);
    OUT[g * 2 + 0] = e0 * si;
    OUT[g * 2 + 1] = e1 * si;
}

extern "C" void kernel_launch(void* const* d_in, const int* in_sizes, int n_in,
                              void* d_out, int out_size, void* d_ws, size_t ws_size,
                              hipStream_t stream)
{
    const float* x    = (const float*)d_in[0];
    const float* ew   = (const float*)d_in[1];
    const int*   er   = (const int*)d_in[2];
    const int*   ec   = (const int*)d_in[3];
    const int*   seg  = (const int*)d_in[4];
    const float* w1_1 = (const float*)d_in[5];
    const float* w2_1 = (const float*)d_in[6];
    const float* b_1  = (const float*)d_in[7];
    const float* w1_2 = (const float*)d_in[8];
    const float* w2_2 = (const float*)d_in[9];
    const float* b_2  = (const float*)d_in[10];
    const float* w1_3 = (const float*)d_in[11];
    const float* w2_3 = (const float*)d_in[12];
    const float* b_3  = (const float*)d_in[13];
    const float* wd   = (const float*)d_in[14];
    const float* bd   = (const float*)d_in[15];

    float* ws = (float*)d_ws;
    int*   IW = (int*)d_ws;
    // Fully disjoint workspace — no aliasing hazards.
    __half* XPh    = (__half*)ws;                   // N x 32 fp16
    uint2*  tmp    = (uint2*)(ws + 1600000);        // E x 8B (sd, w16)
    __half* H2h    = (__half*)(ws + 3200000);       // N x 64 fp16
    __half* A2h    = (__half*)(ws + 4800000);       // N x 64 fp16
    __half* H3h    = (__half*)(ws + 6400000);       // N x 32 fp16
    __half* B2h    = (__half*)(ws + 7200000);       // N x 32 fp16
    unsigned int* packed = (unsigned int*)(IW + 8000000);  // E x 4B
    int*    rowptr = IW + 9000000;                  // N+1
    int*    ghist  = IW + 9060000;                  // NCB*256
    int*    bsum   = IW + 9115000;                  // NCB
    int*    start  = IW + 9120000;                  // G+1
    __half* W1f    = (__half*)(ws + 9125000);       // 64x128 f16 frag-packed
    __half* W2f    = (__half*)(ws + 9130000);       // 128x128 f16 frag-packed
    __half* W3f    = (__half*)(ws + 9139000);       // 64x64 f16 frag-packed
    float*  PS     = ws + 9145000;                  // G x 32 fp32 pooled sums

    dim3 blk(256);

    // ---- CSR build + prep (4 dispatches) ----
    hist_prep<<<dim3(256 + 782 + 196 + 112 + 32), blk, 0, stream>>>(
        er, x, seg, w1_1, w2_1, w1_2, w2_2, w1_3, w2_3,
        ghist, XPh, start, W1f, W2f, W3f, PS);
    scan1<<<dim3(NCB), blk, 0, stream>>>(ghist, bsum);
    c_scatter<<<dim3(256), blk, 0, stream>>>(er, ec, ew, ghist, bsum, tmp);
    bsort<<<dim3(NCB), dim3(1024), 0, stream>>>(tmp, bsum, packed, rowptr);

    // Layer-1 aggx (S=2 split) + layers 1+2 dense fused on MFMA (8 waves)
    dense12_mfma<<<dim3(MBLK), dim3(512), 0, stream>>>(XPh, rowptr, packed,
                                                       W1f, b_1, W2f, b_2,
                                                       H2h, A2h);
    // Layer-2 SpMM fused with layer-3 dense (16 waves; no A2 round-trip)
    spmm_dense3<<<dim3(MBLK), dim3(1024), 0, stream>>>(H2h, rowptr, packed, A2h,
                                                       W3f, b_3, H3h, B2h);
    // Layer-3 SpMM fused with pooling (S=4; no B2h write-back)
    spmm_pool<<<dim3(MBLK), dim3(1024), 0, stream>>>(H3h, rowptr, packed, B2h,
                                                     seg, PS);
    // Head (1 block)
    head_kernel<<<dim3(1), blk, 0, stream>>>(PS, start, wd, bd, (float*)d_out);
}

// Round 11
// 163.420 us; speedup vs baseline: 1.0833x; 1.0833x over previous
//
#include <hip/hip_runtime.h>
#include <hip/hip_fp16.h>

#define N_NODES 50000
#define N_EDGES 800000
#define N_GRAPHS 256
#define NCB 196        // coarse buckets = ceil(50000/256), dst>>8
#define CHUNK 3125     // edges per block in coarse passes (256 blocks)
#define MBLK 782       // ceil(50000/64)

typedef _Float16 f16x8 __attribute__((ext_vector_type(8)));
typedef float    f32x4 __attribute__((ext_vector_type(4)));

// ---------------------------------------------------------------------------
// hist_prep: blocks 0..255 coarse edge histogram (dst>>8); then vectorized
// XPh pad (8 halves/thread), bounds, fp16 fragment-packed weights.
// ---------------------------------------------------------------------------
__global__ __launch_bounds__(256)
void hist_prep(const int* __restrict__ ER, const float* __restrict__ X,
               const int* __restrict__ SEG,
               const float* __restrict__ W1, const float* __restrict__ W2,
               const float* __restrict__ W12, const float* __restrict__ W22,
               const float* __restrict__ W13, const float* __restrict__ W23,
               int* __restrict__ ghist, __half* __restrict__ XPh,
               int* __restrict__ start,
               __half* __restrict__ W1f, __half* __restrict__ W2f,
               __half* __restrict__ W3f)
{
    int b = blockIdx.x;
    int t = threadIdx.x;
    if (b < 256) {                           // coarse histogram
        __shared__ int h[NCB];
        for (int i = t; i < NCB; i += 256) h[i] = 0;
        __syncthreads();
        int lo = b * CHUNK, hi = lo + CHUNK;
        for (int e = lo + t; e < hi; e += 256) atomicAdd(&h[ER[e] >> 8], 1);
        __syncthreads();
        for (int i = t; i < NCB; i += 256) ghist[i * 256 + b] = h[i];
        return;
    }
    int bid = b - 256;
    if (bid < 782) {                         // pad: XPh fp16, 8 halves/thread
        int idx = bid * 256 + t;             // one uint4 of XPh
        int n = idx >> 2;
        int c4 = idx & 3;
        if (n >= N_NODES) return;
        __half2 hb[4];
        #pragma unroll
        for (int k = 0; k < 4; ++k) {
            int c0 = c4 * 8 + 2 * k;
            float v0 = (c0 < 30) ? X[n * 30 + c0] : 0.f;
            float v1 = (c0 + 1 < 30) ? X[n * 30 + c0 + 1] : 0.f;
            hb[k] = __float22half2_rn(make_float2(v0, v1));
        }
        *(uint4*)(XPh + (size_t)n * 32 + c4 * 8) = *(uint4*)&hb[0];
    } else if (bid < 978) {                  // bounds from sorted seg
        int n = (bid - 782) * 256 + t;
        if (n >= N_NODES) return;
        int g = SEG[n];
        int gprev = (n == 0) ? -1 : SEG[n - 1];
        for (int gg = gprev + 1; gg <= g; ++gg) start[gg] = n;
        if (n == N_NODES - 1)
            for (int gg = g + 1; gg <= N_GRAPHS; ++gg) start[gg] = N_NODES;
    } else {                                 // fragment-packed fp16 weights
        int idx = (bid - 978) * 256 + t;     // 0 .. 28671
        if (idx < 8192) {                    // W1f: 64x128 ([W1_1;pad;W2_1])
            int i = idx & 7, c = (idx >> 3) & 15, g = (idx >> 7) & 3;
            int s = (idx >> 9) & 1, n = idx >> 10;
            int k = s * 32 + g * 8 + i, col = n * 16 + c;
            float w = 0.f;
            if (k < 30) w = W1[k * 128 + col];
            else if (k >= 32 && k < 62) w = W2[(k - 32) * 128 + col];
            W1f[idx] = __float2half(w);
        } else if (idx < 24576) {            // W2f: 128x128 ([W1_2|W2_2])
            int o = idx - 8192;
            int i = o & 7, c = (o >> 3) & 15, g = (o >> 7) & 3;
            int s = (o >> 9) & 3, n = o >> 11;
            int k = s * 32 + g * 8 + i, col = n * 16 + c;
            float w = (col < 64) ? W12[k * 64 + col] : W22[k * 64 + col - 64];
            W2f[o] = __float2half(w);
        } else {                             // W3f: 64x64 ([W1_3|W2_3])
            int o = idx - 24576;
            int i = o & 7, c = (o >> 3) & 15, g = (o >> 7) & 3;
            int s = (o >> 9) & 1, n = o >> 10;
            int k = s * 32 + g * 8 + i, col = n * 16 + c;
            float w = (col < 32) ? W13[k * 32 + col] : W23[k * 32 + col - 32];
            W3f[o] = __float2half(w);
        }
    }
}

// ---------------------------------------------------------------------------
// scan1: per-bucket exclusive scan of the 256 per-block counts, in place;
// bucket total -> bsum[b].
// ---------------------------------------------------------------------------
__global__ __launch_bounds__(256)
void scan1(int* __restrict__ ghist, int* __restrict__ bsum)
{
    __shared__ int s[256];
    int t = threadIdx.x, b = blockIdx.x;
    int i = b * 256 + t;
    int v = ghist[i];
    s[t] = v;
    __syncthreads();
    for (int off = 1; off < 256; off <<= 1) {
        int u = (t >= off) ? s[t - off] : 0;
        __syncthreads();
        s[t] += u;
        __syncthreads();
    }
    ghist[i] = s[t] - v;
    if (t == 255) bsum[b] = s[255];
}

// ---------------------------------------------------------------------------
// c_scatter (1024 thr): coarse scatter into per-block contiguous runs.
// 256 blocks x 1024 threads (~3 edges/thread): 4x the outstanding-miss
// parallelism of the 256-thread version for the scattered 8B stores.
// tmp = { src | ((dst&255)<<16), fp16 weight } as one 8B uint2 store.
// ---------------------------------------------------------------------------
__global__ __launch_bounds__(1024)
void c_scatter(const int* __restrict__ ER, const int* __restrict__ EC,
               const float* __restrict__ EW, const int* __restrict__ ghist,
               const int* __restrict__ bsum, uint2* __restrict__ tmp)
{
    __shared__ int s[256];
    __shared__ int cur[NCB];
    int t = threadIdx.x, blk = blockIdx.x;
    int v = 0;
    if (t < 256) {
        v = (t < NCB) ? bsum[t] : 0;
        s[t] = v;
    }
    __syncthreads();
    for (int off = 1; off < 256; off <<= 1) {
        int u = 0;
        if (t < 256 && t >= off) u = s[t - off];
        __syncthreads();
        if (t < 256) s[t] += u;
        __syncthreads();
    }
    if (t < NCB) cur[t] = (s[t] - v) + ghist[t * 256 + blk];
    __syncthreads();
    int lo = blk * CHUNK, hi = lo + CHUNK;
    for (int e = lo + t; e < hi; e += 1024) {
        int d = ER[e];
        int pos = atomicAdd(&cur[d >> 8], 1);
        tmp[pos] = make_uint2((unsigned int)EC[e] | ((unsigned int)(d & 255) << 16),
                              (unsigned int)__half_as_ushort(__float2half(EW[e])));
    }
}

// ---------------------------------------------------------------------------
// fp16 gather helper
// ---------------------------------------------------------------------------
__device__ __forceinline__ void fma8h(float4& a0, float4& a1, float w,
                                      const uint4& raw)
{
    const __half2* hp = (const __half2*)&raw;
    float2 f0 = __half22float2(hp[0]);
    float2 f1 = __half22float2(hp[1]);
    float2 f2 = __half22float2(hp[2]);
    float2 f3 = __half22float2(hp[3]);
    a0.x = fmaf(w, f0.x, a0.x); a0.y = fmaf(w, f0.y, a0.y);
    a0.z = fmaf(w, f1.x, a0.z); a0.w = fmaf(w, f1.y, a0.w);
    a1.x = fmaf(w, f2.x, a1.x); a1.y = fmaf(w, f2.y, a1.y);
    a1.z = fmaf(w, f3.x, a1.z); a1.w = fmaf(w, f3.y, a1.w);
}

// ---------------------------------------------------------------------------
// bsort (1024 thr): per-bucket counting sort -> packed + rowptr.
// ---------------------------------------------------------------------------
__global__ __launch_bounds__(1024)
void bsort(const uint2* __restrict__ tmp, const int* __restrict__ bsum,
           unsigned int* __restrict__ packed, int* __restrict__ rowptr)
{
    __shared__ int s[256];
    __shared__ int hist[256];
    __shared__ int cur[256];
    int t = threadIdx.x, b = blockIdx.x;

    if (t < 256) s[t] = (t < NCB) ? bsum[t] : 0;
    __syncthreads();
    for (int off = 1; off < 256; off <<= 1) {
        int u = 0;
        if (t < 256 && t >= off) u = s[t - off];
        __syncthreads();
        if (t < 256) s[t] += u;
        __syncthreads();
    }
    int cntb = bsum[b];
    int base = s[b] - cntb;
    int end  = base + cntb;
    __syncthreads();

    if (t < 256) hist[t] = 0;
    __syncthreads();
    for (int j = base + t; j < end; j += 1024)
        atomicAdd(&hist[(tmp[j].x >> 16) & 255], 1);
    __syncthreads();
    int hv = 0;
    if (t < 256) { hv = hist[t]; s[t] = hv; }
    __syncthreads();
    for (int off = 1; off < 256; off <<= 1) {
        int u = 0;
        if (t < 256 && t >= off) u = s[t - off];
        __syncthreads();
        if (t < 256) s[t] += u;
        __syncthreads();
    }
    if (t < 256) {
        int excl = s[t] - hv;
        int n = b * 256 + t;
        if (n < N_NODES) rowptr[n] = base + excl;
        if (b == NCB - 1 && t == 0) rowptr[N_NODES] = N_EDGES;
        cur[t] = base + excl;
    }
    __syncthreads();
    for (int j = base + t; j < end; j += 1024) {
        uint2 v = tmp[j];
        int pos = atomicAdd(&cur[(v.x >> 16) & 255], 1);
        packed[pos] = (v.x & 0xFFFF) | (v.y << 16);
    }
}

// ---------------------------------------------------------------------------
// dense12_mfma (512 thr): layer-1 aggx (S=2 edge split) FUSED with layers 1+2
// dense on matrix cores, 8 waves. (R9-verified)
// ---------------------------------------------------------------------------
__global__ __launch_bounds__(512)
void dense12_mfma(const __half* __restrict__ XPh, const int* __restrict__ rowptr,
                  const unsigned int* __restrict__ packed,
                  const __half* __restrict__ W1f, const float* __restrict__ B1,
                  const __half* __restrict__ W2f, const float* __restrict__ B2,
                  __half* __restrict__ H2h, __half* __restrict__ A2h)
{
    __shared__ __align__(16) __half As[64 * 72];    // input tile, stride 72
    __shared__ __align__(16) __half Hs[64 * 136];   // partials / h1 / output
    const int tid = threadIdx.x;
    const int m0 = blockIdx.x * 64;

    // phase 0a: stage XPh half (cols 32-63): 64 rows x 4 uint4 = 256 threads
    if (tid < 256) {
        int row = tid >> 2, c4 = tid & 3;
        int gm = m0 + row;
        uint4 v = make_uint4(0, 0, 0, 0);
        if (gm < N_NODES) v = *(const uint4*)(XPh + (size_t)gm * 32 + c4 * 8);
        *(uint4*)(As + row * 72 + (4 + c4) * 8) = v;
    }
    // phase 0b: layer-1 aggx, S=2 edge split: 64 nodes x 2 seg x 4 lanes.
    {
        int local = tid >> 3;          // node 0..63
        int es = (tid >> 2) & 1;       // edge segment
        int q = tid & 3;               // feature quad
        int n = m0 + local;
        float4 acc0 = make_float4(0.f, 0.f, 0.f, 0.f);
        float4 acc1 = make_float4(0.f, 0.f, 0.f, 0.f);
        if (n < N_NODES) {
            int r0 = rowptr[n], r1 = rowptr[n + 1];
            int mid = (r0 + r1) >> 1;
            int lo = es ? mid : r0;
            int hi = es ? r1 : mid;
            int j = lo;
            for (; j + 3 < hi; j += 4) {
                unsigned int ra = packed[j],     rb = packed[j + 1];
                unsigned int rc = packed[j + 2], rd = packed[j + 3];
                uint4 rawa = *(const uint4*)(XPh + (size_t)(ra & 0xFFFF) * 32 + q * 8);
                uint4 rawb = *(const uint4*)(XPh + (size_t)(rb & 0xFFFF) * 32 + q * 8);
                uint4 rawc = *(const uint4*)(XPh + (size_t)(rc & 0xFFFF) * 32 + q * 8);
                uint4 rawd = *(const uint4*)(XPh + (size_t)(rd & 0xFFFF) * 32 + q * 8);
                float wa = __half2float(__ushort_as_half((unsigned short)(ra >> 16)));
                float wb = __half2float(__ushort_as_half((unsigned short)(rb >> 16)));
                float wc = __half2float(__ushort_as_half((unsigned short)(rc >> 16)));
                float wd = __half2float(__ushort_as_half((unsigned short)(rd >> 16)));
                fma8h(acc0, acc1, wa, rawa);
                fma8h(acc0, acc1, wb, rawb);
                fma8h(acc0, acc1, wc, rawc);
                fma8h(acc0, acc1, wd, rawd);
            }
            for (; j < hi; ++j) {
                unsigned int r = packed[j];
                uint4 raw = *(const uint4*)(XPh + (size_t)(r & 0xFFFF) * 32 + q * 8);
                float wv = __half2float(__ushort_as_half((unsigned short)(r >> 16)));
                fma8h(acc0, acc1, wv, raw);
            }
        }
        float* part = (float*)Hs;      // 64 x 36 fp32 (9.2 KB < 17.4 KB)
        if (es == 1) {
            *(float4*)&part[local * 36 + q * 8 + 0] = acc0;
            *(float4*)&part[local * 36 + q * 8 + 4] = acc1;
        }
        __syncthreads();               // partials + 0a staging visible
        if (es == 0) {
            float4 p0 = *(float4*)&part[local * 36 + q * 8 + 0];
            float4 p1 = *(float4*)&part[local * 36 + q * 8 + 4];
            acc0.x += p0.x; acc0.y += p0.y; acc0.z += p0.z; acc0.w += p0.w;
            acc1.x += p1.x; acc1.y += p1.y; acc1.z += p1.z; acc1.w += p1.w;
            __half2 hb2[4];
            hb2[0] = __float22half2_rn(make_float2(acc0.x, acc0.y));
            hb2[1] = __float22half2_rn(make_float2(acc0.z, acc0.w));
            hb2[2] = __float22half2_rn(make_float2(acc1.x, acc1.y));
            hb2[3] = __float22half2_rn(make_float2(acc1.z, acc1.w));
            *(uint4*)(As + local * 72 + q * 8) = *(uint4*)&hb2[0];
        }
    }
    __syncthreads();                   // As complete; Hs free for h1

    const int lane = tid & 63;
    const int w  = tid >> 6;           // wave 0..7, owns n-subtile w
    const int lr = lane & 15;
    const int lg = lane >> 4;

    // phase A: K=64 (2 MFMA K-slices), 8 MFMAs/wave
    f32x4 acc[4];
    #pragma unroll
    for (int m = 0; m < 4; ++m) acc[m] = (f32x4){0.f, 0.f, 0.f, 0.f};

    #pragma unroll
    for (int s = 0; s < 2; ++s) {
        f16x8 b = *(const f16x8*)(W1f + (((w * 2 + s) * 4 + lg) * 16 + lr) * 8);
        #pragma unroll
        for (int m = 0; m < 4; ++m) {
            f16x8 a = *(const f16x8*)(As + (m * 16 + lr) * 72 + s * 32 + lg * 8);
            acc[m] = __builtin_amdgcn_mfma_f32_16x16x32_f16(a, b, acc[m], 0, 0, 0);
        }
    }

    // +b1, relu, h1 -> LDS fp16
    {
        const float bias = B1[w * 16 + lr];
        #pragma unroll
        for (int m = 0; m < 4; ++m)
            #pragma unroll
            for (int r = 0; r < 4; ++r) {
                float v = fmaxf(acc[m][r] + bias, 0.f);
                Hs[(m * 16 + lg * 4 + r) * 136 + w * 16 + lr] = __float2half(v);
            }
    }
    __syncthreads();

    // phase B: K=128 (4 slices), 16 MFMAs/wave
    f32x4 acc2[4];
    #pragma unroll
    for (int m = 0; m < 4; ++m) acc2[m] = (f32x4){0.f, 0.f, 0.f, 0.f};

    #pragma unroll
    for (int s = 0; s < 4; ++s) {
        f16x8 b = *(const f16x8*)(W2f + (((w * 4 + s) * 4 + lg) * 16 + lr) * 8);
        #pragma unroll
        for (int m = 0; m < 4; ++m) {
            f16x8 a = *(const f16x8*)(Hs + (m * 16 + lr) * 136 + s * 32 + lg * 8);
            acc2[m] = __builtin_amdgcn_mfma_f32_16x16x32_f16(a, b, acc2[m], 0, 0, 0);
        }
    }
    __syncthreads();   // all h1 reads done; Hs reusable for output

    {
        const float bias = (w >= 4) ? B2[(w - 4) * 16 + lr] : 0.f;
        #pragma unroll
        for (int m = 0; m < 4; ++m)
            #pragma unroll
            for (int r = 0; r < 4; ++r)
                Hs[(m * 16 + lg * 4 + r) * 136 + w * 16 + lr] =
                    __float2half(acc2[m][r] + bias);
    }
    __syncthreads();

    // coalesced fp16 store: cols 0-63 -> H2h, 64-127 -> A2h
    for (int idx = tid; idx < 1024; idx += 512) {
        int row = idx >> 4, c8 = idx & 15;
        int gm = m0 + row;
        if (gm < N_NODES) {
            uint4 v = *(const uint4*)(Hs + row * 136 + c8 * 8);
            if (c8 < 8) *(uint4*)(H2h + (size_t)gm * 64 + c8 * 8) = v;
            else        *(uint4*)(A2h + (size_t)gm * 64 + (c8 - 8) * 8) = v;
        }
    }
}

// ---------------------------------------------------------------------------
// spmm_dense3 (1024 thr): layer-2 SpMM (S=2 edge split, 16 thr/node) FUSED
// with layer-3 dense on matrix cores (16 waves). (R9-verified)
// ---------------------------------------------------------------------------
__global__ __launch_bounds__(1024)
void spmm_dense3(const __half* __restrict__ H2h, const int* __restrict__ rowptr,
                 const unsigned int* __restrict__ packed,
                 const __half* __restrict__ A2h, const __half* __restrict__ W3f,
                 const float* __restrict__ B3, __half* __restrict__ H3h,
                 __half* __restrict__ B2h)
{
    __shared__ __align__(16) __half As[64 * 72];    // relu'd layer-2 act tile
    __shared__ __align__(16) __half Os[64 * 72];    // output tile
    __shared__ float part[64][68];                  // s=1 partials (17.4 KB)
    const int tid = threadIdx.x;
    const int m0 = blockIdx.x * 64;

    // ---- phase 1: SpMM, 64 nodes x 2 segments x 8 lanes ----
    {
        int local = tid >> 4;          // node 0..63
        int es = (tid >> 3) & 1;       // edge segment
        int q = tid & 7;               // feature octet (64 cols)
        int n = m0 + local;
        float4 acc0 = make_float4(0.f, 0.f, 0.f, 0.f);
        float4 acc1 = make_float4(0.f, 0.f, 0.f, 0.f);
        if (n < N_NODES) {
            int r0 = rowptr[n], r1 = rowptr[n + 1];
            int mid = (r0 + r1) >> 1;
            int lo = es ? mid : r0;
            int hi = es ? r1 : mid;
            if (es == 0) {             // init from A2h (x @ W2_2 + b2 part)
                uint4 raw = *(const uint4*)(A2h + (size_t)n * 64 + q * 8);
                const __half2* hp = (const __half2*)&raw;
                float2 f0 = __half22float2(hp[0]);
                float2 f1 = __half22float2(hp[1]);
                float2 f2 = __half22float2(hp[2]);
                float2 f3 = __half22float2(hp[3]);
                acc0 = make_float4(f0.x, f0.y, f1.x, f1.y);
                acc1 = make_float4(f2.x, f2.y, f3.x, f3.y);
            }
            int j = lo;
            for (; j + 3 < hi; j += 4) {
                unsigned int ra = packed[j],     rb = packed[j + 1];
                unsigned int rc = packed[j + 2], rd = packed[j + 3];
                uint4 rawa = *(const uint4*)(H2h + (size_t)(ra & 0xFFFF) * 64 + q * 8);
                uint4 rawb = *(const uint4*)(H2h + (size_t)(rb & 0xFFFF) * 64 + q * 8);
                uint4 rawc = *(const uint4*)(H2h + (size_t)(rc & 0xFFFF) * 64 + q * 8);
                uint4 rawd = *(const uint4*)(H2h + (size_t)(rd & 0xFFFF) * 64 + q * 8);
                float wa = __half2float(__ushort_as_half((unsigned short)(ra >> 16)));
                float wb = __half2float(__ushort_as_half((unsigned short)(rb >> 16)));
                float wc = __half2float(__ushort_as_half((unsigned short)(rc >> 16)));
                float wd = __half2float(__ushort_as_half((unsigned short)(rd >> 16)));
                fma8h(acc0, acc1, wa, rawa);
                fma8h(acc0, acc1, wb, rawb);
                fma8h(acc0, acc1, wc, rawc);
                fma8h(acc0, acc1, wd, rawd);
            }
            for (; j < hi; ++j) {
                unsigned int r = packed[j];
                uint4 raw = *(const uint4*)(H2h + (size_t)(r & 0xFFFF) * 64 + q * 8);
                float w = __half2float(__ushort_as_half((unsigned short)(r >> 16)));
                fma8h(acc0, acc1, w, raw);
            }
        }
        if (es == 1) {
            *(float4*)&part[local][q * 8 + 0] = acc0;
            *(float4*)&part[local][q * 8 + 4] = acc1;
        }
        __syncthreads();
        if (es == 0) {
            float4 p0 = *(float4*)&part[local][q * 8 + 0];
            float4 p1 = *(float4*)&part[local][q * 8 + 4];
            acc0.x += p0.x; acc0.y += p0.y; acc0.z += p0.z; acc0.w += p0.w;
            acc1.x += p1.x; acc1.y += p1.y; acc1.z += p1.z; acc1.w += p1.w;
            // relu + fp16 pack straight into the MFMA A-tile
            __half2 hb[4];
            hb[0] = __float22half2_rn(make_float2(fmaxf(acc0.x, 0.f), fmaxf(acc0.y, 0.f)));
            hb[1] = __float22half2_rn(make_float2(fmaxf(acc0.z, 0.f), fmaxf(acc0.w, 0.f)));
            hb[2] = __float22half2_rn(make_float2(fmaxf(acc1.x, 0.f), fmaxf(acc1.y, 0.f)));
            hb[3] = __float22half2_rn(make_float2(fmaxf(acc1.z, 0.f), fmaxf(acc1.w, 0.f)));
            *(uint4*)(As + local * 72 + q * 8) = *(uint4*)&hb[0];
        }
    }
    __syncthreads();

    // ---- phase 2: dense3 MFMA, 16 waves; wave w = (m-quarter w>>2, n w&3) ----
    const int lane = tid & 63;
    const int w  = tid >> 6;      // 0..15
    const int wm = w >> 2;        // m quarter
    const int wn = w & 3;         // n subtile
    const int lr = lane & 15;
    const int lg = lane >> 4;

    f32x4 acc = (f32x4){0.f, 0.f, 0.f, 0.f};
    #pragma unroll
    for (int s = 0; s < 2; ++s) {
        f16x8 b = *(const f16x8*)(W3f + (((wn * 2 + s) * 4 + lg) * 16 + lr) * 8);
        f16x8 a = *(const f16x8*)(As + (wm * 16 + lr) * 72 + s * 32 + lg * 8);
        acc = __builtin_amdgcn_mfma_f32_16x16x32_f16(a, b, acc, 0, 0, 0);
    }

    const float bias = (wn >= 2) ? B3[(wn - 2) * 16 + lr] : 0.f;
    #pragma unroll
    for (int r = 0; r < 4; ++r)
        Os[(wm * 16 + lg * 4 + r) * 72 + wn * 16 + lr] = __float2half(acc[r] + bias);
    __syncthreads();

    // store: 64 rows x 8 uint4 = 512 entries
    if (tid < 512) {
        int row = tid >> 3, c8 = tid & 7;
        int gm = m0 + row;
        if (gm < N_NODES) {
            uint4 v = *(const uint4*)(Os + row * 72 + c8 * 8);
            if (c8 < 4) *(uint4*)(H3h + (size_t)gm * 32 + c8 * 8) = v;
            else        *(uint4*)(B2h + (size_t)gm * 32 + (c8 - 4) * 8) = v;
        }
    }
}

// ---------------------------------------------------------------------------
// spmm_split (512 thr, S segments): edge-split SpMM with fp32 RMW on fp16 AGG.
// ---------------------------------------------------------------------------
template<int FOUT, int S>
__global__ __launch_bounds__(512)
void spmm_split(const __half* __restrict__ H, const int* __restrict__ rowptr,
                const unsigned int* __restrict__ packed, __half* __restrict__ AGGh)
{
    constexpr int T = FOUT / 8;          // lanes per node per segment
    constexpr int NPB = 512 / (S * T);   // nodes per block
    __shared__ float part[NPB][S - 1][FOUT + 4];
    int tid = threadIdx.x;
    int local = tid / (S * T);
    int rem = tid % (S * T);
    int s = rem / T;
    int q = rem % T;
    int n = blockIdx.x * NPB + local;
    bool valid = (n < N_NODES);
    float4 acc0 = make_float4(0.f, 0.f, 0.f, 0.f);
    float4 acc1 = make_float4(0.f, 0.f, 0.f, 0.f);
    __half* ap = AGGh + (size_t)n * FOUT + q * 8;
    if (valid) {
        int r0 = rowptr[n], r1 = rowptr[n + 1];
        int deg = r1 - r0;
        int lo = r0 + (deg * s) / S;
        int hi = r0 + (deg * (s + 1)) / S;
        if (s == 0) {                      // init from existing AGG row
            uint4 raw = *(const uint4*)ap;
            const __half2* hp = (const __half2*)&raw;
            float2 f0 = __half22float2(hp[0]);
            float2 f1 = __half22float2(hp[1]);
            float2 f2 = __half22float2(hp[2]);
            float2 f3 = __half22float2(hp[3]);
            acc0 = make_float4(f0.x, f0.y, f1.x, f1.y);
            acc1 = make_float4(f2.x, f2.y, f3.x, f3.y);
        }
        int j = lo;
        for (; j + 3 < hi; j += 4) {
            unsigned int ra = packed[j],     rb = packed[j + 1];
            unsigned int rc = packed[j + 2], rd = packed[j + 3];
            uint4 rawa = *(const uint4*)(H + (size_t)(ra & 0xFFFF) * FOUT + q * 8);
            uint4 rawb = *(const uint4*)(H + (size_t)(rb & 0xFFFF) * FOUT + q * 8);
            uint4 rawc = *(const uint4*)(H + (size_t)(rc & 0xFFFF) * FOUT + q * 8);
            uint4 rawd = *(const uint4*)(H + (size_t)(rd & 0xFFFF) * FOUT + q * 8);
            float wa = __half2float(__ushort_as_half((unsigned short)(ra >> 16)));
            float wb = __half2float(__ushort_as_half((unsigned short)(rb >> 16)));
            float wc = __half2float(__ushort_as_half((unsigned short)(rc >> 16)));
            float wd = __half2float(__ushort_as_half((unsigned short)(rd >> 16)));
            fma8h(acc0, acc1, wa, rawa);
            fma8h(acc0, acc1, wb, rawb);
            fma8h(acc0, acc1, wc, rawc);
            fma8h(acc0, acc1, wd, rawd);
        }
        for (; j < hi; ++j) {
            unsigned int r = packed[j];
            uint4 raw = *(const uint4*)(H + (size_t)(r & 0xFFFF) * FOUT + q * 8);
            float w = __half2float(__ushort_as_half((unsigned short)(r >> 16)));
            fma8h(acc0, acc1, w, raw);
        }
    }
    if (s > 0) {
        *(float4*)&part[local][s - 1][q * 8 + 0] = acc0;
        *(float4*)&part[local][s - 1][q * 8 + 4] = acc1;
    }
    __syncthreads();
    if (s == 0 && valid) {
        #pragma unroll
        for (int ss = 0; ss < S - 1; ++ss) {
            float4 p0 = *(float4*)&part[local][ss][q * 8 + 0];
            float4 p1 = *(float4*)&part[local][ss][q * 8 + 4];
            acc0.x += p0.x; acc0.y += p0.y; acc0.z += p0.z; acc0.w += p0.w;
            acc1.x += p1.x; acc1.y += p1.y; acc1.z += p1.z; acc1.w += p1.w;
        }
        __half2 hb[4];
        hb[0] = __float22half2_rn(make_float2(acc0.x, acc0.y));
        hb[1] = __float22half2_rn(make_float2(acc0.z, acc0.w));
        hb[2] = __float22half2_rn(make_float2(acc1.x, acc1.y));
        hb[3] = __float22half2_rn(make_float2(acc1.z, acc1.w));
        *(uint4*)ap = *(uint4*)&hb[0];
    }
}

// ---------------------------------------------------------------------------
// pool + head fused (1024 thr): 32-way node-parallel per graph; mean of
// relu(B2h fp16), softmax(p@wd+bd).
// ---------------------------------------------------------------------------
__global__ __launch_bounds__(1024)
void pool_kernel(const __half* __restrict__ H, const int* __restrict__ start,
                 const float* __restrict__ WD, const float* __restrict__ BD,
                 float* __restrict__ OUT)
{
    __shared__ float red[32][33];
    int g = blockIdx.x;
    int s = start[g], e = start[g + 1];
    int q = threadIdx.x & 31;
    int grp = threadIdx.x >> 5;
    float acc = 0.f;
    for (int n = s + grp; n < e; n += 32)
        acc += fmaxf(__half2float(H[(size_t)n * 32 + q]), 0.f);
    red[grp][q] = acc;
    __syncthreads();
    if (threadIdx.x < 32) {
        float v = 0.f;
        #pragma unroll
        for (int i = 0; i < 32; ++i) v += red[i][q];
        float inv = (e > s) ? 1.0f / (float)(e - s) : 1.0f;
        float p = v * inv;
        float p0 = p * WD[q * 2 + 0];
        float p1 = p * WD[q * 2 + 1];
        #pragma unroll
        for (int off = 16; off; off >>= 1) {
            p0 += __shfl_down(p0, off, 32);
            p1 += __shfl_down(p1, off, 32);
        }
        if (q == 0) {
            float l0 = p0 + BD[0], l1 = p1 + BD[1];
            float m = fmaxf(l0, l1);
            float e0 = expf(l0 - m), e1 = expf(l1 - m);
            float si = 1.0f / (e0 + e1);
            OUT[g * 2 + 0] = e0 * si;
            OUT[g * 2 + 1] = e1 * si;
        }
    }
}

extern "C" void kernel_launch(void* const* d_in, const int* in_sizes, int n_in,
                              void* d_out, int out_size, void* d_ws, size_t ws_size,
                              hipStream_t stream)
{
    const float* x    = (const float*)d_in[0];
    const float* ew   = (const float*)d_in[1];
    const int*   er   = (const int*)d_in[2];
    const int*   ec   = (const int*)d_in[3];
    const int*   seg  = (const int*)d_in[4];
    const float* w1_1 = (const float*)d_in[5];
    const float* w2_1 = (const float*)d_in[6];
    const float* b_1  = (const float*)d_in[7];
    const float* w1_2 = (const float*)d_in[8];
    const float* w2_2 = (const float*)d_in[9];
    const float* b_2  = (const float*)d_in[10];
    const float* w1_3 = (const float*)d_in[11];
    const float* w2_3 = (const float*)d_in[12];
    const float* b_3  = (const float*)d_in[13];
    const float* wd   = (const float*)d_in[14];
    const float* bd   = (const float*)d_in[15];

    float* ws = (float*)d_ws;
    int*   IW = (int*)d_ws;
    // Fully disjoint workspace — no aliasing hazards.
    __half* XPh    = (__half*)ws;                   // N x 32 fp16
    uint2*  tmp    = (uint2*)(ws + 1600000);        // E x 8B (sd, w16)
    __half* H2h    = (__half*)(ws + 3200000);       // N x 64 fp16
    __half* A2h    = (__half*)(ws + 4800000);       // N x 64 fp16
    __half* H3h    = (__half*)(ws + 6400000);       // N x 32 fp16
    __half* B2h    = (__half*)(ws + 7200000);       // N x 32 fp16
    unsigned int* packed = (unsigned int*)(IW + 8000000);  // E x 4B
    int*    rowptr = IW + 9000000;                  // N+1
    int*    ghist  = IW + 9060000;                  // NCB*256
    int*    bsum   = IW + 9115000;                  // NCB
    int*    start  = IW + 9120000;                  // G+1
    __half* W1f    = (__half*)(ws + 9125000);       // 64x128 f16 frag-packed
    __half* W2f    = (__half*)(ws + 9130000);       // 128x128 f16 frag-packed
    __half* W3f    = (__half*)(ws + 9139000);       // 64x64 f16 frag-packed

    dim3 blk(256);

    // ---- CSR build + prep (4 dispatches) ----
    hist_prep<<<dim3(256 + 782 + 196 + 112), blk, 0, stream>>>(
        er, x, seg, w1_1, w2_1, w1_2, w2_2, w1_3, w2_3,
        ghist, XPh, start, W1f, W2f, W3f);
    scan1<<<dim3(NCB), blk, 0, stream>>>(ghist, bsum);
    c_scatter<<<dim3(256), dim3(1024), 0, stream>>>(er, ec, ew, ghist, bsum, tmp);
    bsort<<<dim3(NCB), dim3(1024), 0, stream>>>(tmp, bsum, packed, rowptr);

    // Layer-1 aggx (S=2 split) + layers 1+2 dense fused on MFMA (8 waves)
    dense12_mfma<<<dim3(MBLK), dim3(512), 0, stream>>>(XPh, rowptr, packed,
                                                       W1f, b_1, W2f, b_2,
                                                       H2h, A2h);
    // Layer-2 SpMM fused with layer-3 dense (16 waves; no A2 round-trip)
    spmm_dense3<<<dim3(MBLK), dim3(1024), 0, stream>>>(H2h, rowptr, packed, A2h,
                                                       W3f, b_3, H3h, B2h);
    // Layer-3 SpMM: S=4 edge split
    spmm_split<32, 4><<<dim3((N_NODES + 31) / 32), dim3(512), 0, stream>>>(H3h, rowptr,
                                                                           packed, B2h);

    // Pool + head (fused, atomic-free, 32-way node-parallel)
    pool_kernel<<<dim3(N_GRAPHS), dim3(1024), 0, stream>>>(B2h, start, wd, bd,
                                                           (float*)d_out);
}